// Round 1
// baseline (1311.991 us; speedup 1.0000x reference)
//
#include <hip/hip_runtime.h>
#include <math.h>

// Problem constants
// B=4, N1=2048, N2=1024, IN=768, OUT=1024, H=16, DH=64
// out = concat(att_probs [4,16,1024,2048] fp32, out [4,1024,1024] fp32)

__device__ __forceinline__ float wave_red_sum(float v) {
#pragma unroll
  for (int o = 32; o; o >>= 1) v += __shfl_down(v, o);
  return v;
}
__device__ __forceinline__ float wave_red_max(float v) {
#pragma unroll
  for (int o = 32; o; o >>= 1) v = fmaxf(v, __shfl_down(v, o));
  return v;
}

// ---------------- LayerNorm: one block per row ----------------
__global__ __launch_bounds__(256) void ln_kernel(
    const float* __restrict__ src, const float* __restrict__ g,
    const float* __restrict__ bta, float* __restrict__ dst, int D) {
  size_t row = blockIdx.x;
  const float* x = src + row * (size_t)D;
  float* y = dst + row * (size_t)D;
  int nv = D >> 2;
  float s = 0.f, s2 = 0.f;
  for (int i = threadIdx.x; i < nv; i += 256) {
    float4 v = ((const float4*)x)[i];
    s += v.x + v.y + v.z + v.w;
    s2 += v.x * v.x + v.y * v.y + v.z * v.z + v.w * v.w;
  }
  s = wave_red_sum(s);
  s2 = wave_red_sum(s2);
  __shared__ float red[8];
  int wid = threadIdx.x >> 6, lane = threadIdx.x & 63;
  if (lane == 0) { red[wid] = s; red[4 + wid] = s2; }
  __syncthreads();
  float ts = red[0] + red[1] + red[2] + red[3];
  float t2 = red[4] + red[5] + red[6] + red[7];
  float mu = ts / (float)D;
  float rstd = rsqrtf(t2 / (float)D - mu * mu + 1e-5f);
  for (int i = threadIdx.x; i < nv; i += 256) {
    float4 v = ((const float4*)x)[i];
    float4 gg = ((const float4*)g)[i];
    float4 bb = ((const float4*)bta)[i];
    float4 o;
    o.x = (v.x - mu) * rstd * gg.x + bb.x;
    o.y = (v.y - mu) * rstd * gg.y + bb.y;
    o.z = (v.z - mu) * rstd * gg.z + bb.z;
    o.w = (v.w - mu) * rstd * gg.w + bb.w;
    ((float4*)y)[i] = o;
  }
}

// ---------------- Generic batched fp32 GEMM ----------------
// C[m][n] = alpha * sum_k A[m][k] * W_eff[n][k] + bias[n] + resid[m][n]
// W_KN=false: W stored [N,K] row-major (weights W.T multiply)
// W_KN=true : W stored [K,N] row-major (e.g. V for P@V)
// Batch z: base += (z/zdiv)*s1 + (z%zdiv)*s2 for each of A,W,C.
template <bool W_KN>
__global__ __launch_bounds__(256) void gemm_kernel(
    const float* __restrict__ A, const float* __restrict__ W,
    const float* __restrict__ bias, const float* __restrict__ resid,
    float* __restrict__ C, int M, int N, int K, int lda, int ldw, int ldc,
    long long sA1, long long sA2, long long sW1, long long sW2, long long sC1,
    long long sC2, int zdiv, float alpha) {
  __shared__ float As[16][68];
  __shared__ float Ws[16][68];
  int z = blockIdx.z;
  int zb = z / zdiv, zh = z % zdiv;
  const float* Ab = A + (size_t)zb * sA1 + (size_t)zh * sA2;
  const float* Wb = W + (size_t)zb * sW1 + (size_t)zh * sW2;
  float* Cb = C + (size_t)zb * sC1 + (size_t)zh * sC2;

  int tid = threadIdx.x;
  int tx = tid & 15, ty = tid >> 4;
  int m0 = blockIdx.x * 64, n0 = blockIdx.y * 64;

  float acc[4][4] = {};

  int r = tid >> 2, c4 = (tid & 3) * 4;
  for (int k0 = 0; k0 < K; k0 += 16) {
    float4 a = *(const float4*)(Ab + (size_t)(m0 + r) * lda + k0 + c4);
    As[c4 + 0][r] = a.x;
    As[c4 + 1][r] = a.y;
    As[c4 + 2][r] = a.z;
    As[c4 + 3][r] = a.w;
    if (W_KN) {
      int wk = tid >> 4, wn = (tid & 15) * 4;
      float4 w = *(const float4*)(Wb + (size_t)(k0 + wk) * ldw + n0 + wn);
      Ws[wk][wn + 0] = w.x;
      Ws[wk][wn + 1] = w.y;
      Ws[wk][wn + 2] = w.z;
      Ws[wk][wn + 3] = w.w;
    } else {
      float4 w = *(const float4*)(Wb + (size_t)(n0 + r) * ldw + k0 + c4);
      Ws[c4 + 0][r] = w.x;
      Ws[c4 + 1][r] = w.y;
      Ws[c4 + 2][r] = w.z;
      Ws[c4 + 3][r] = w.w;
    }
    __syncthreads();
#pragma unroll
    for (int kk = 0; kk < 16; ++kk) {
      float4 av = *(const float4*)&As[kk][ty * 4];
      float4 wv = *(const float4*)&Ws[kk][tx * 4];
      float aa[4] = {av.x, av.y, av.z, av.w};
      float ww[4] = {wv.x, wv.y, wv.z, wv.w};
#pragma unroll
      for (int i = 0; i < 4; ++i)
#pragma unroll
        for (int j = 0; j < 4; ++j) acc[i][j] = fmaf(aa[i], ww[j], acc[i][j]);
    }
    __syncthreads();
  }

  float4 bv = make_float4(0.f, 0.f, 0.f, 0.f);
  if (bias) bv = *(const float4*)(bias + n0 + tx * 4);
#pragma unroll
  for (int i = 0; i < 4; ++i) {
    int m = m0 + ty * 4 + i;
    float4 o;
    o.x = acc[i][0] * alpha + bv.x;
    o.y = acc[i][1] * alpha + bv.y;
    o.z = acc[i][2] * alpha + bv.z;
    o.w = acc[i][3] * alpha + bv.w;
    if (resid) {
      float4 rv = *(const float4*)(resid + (size_t)m * ldc + n0 + tx * 4);
      o.x += rv.x;
      o.y += rv.y;
      o.z += rv.z;
      o.w += rv.w;
    }
    *(float4*)(Cb + (size_t)m * ldc + n0 + tx * 4) = o;
  }
}

// ---------------- Row softmax, in place, row length 2048 ----------------
__global__ __launch_bounds__(256) void softmax_kernel(float* __restrict__ att) {
  size_t row = blockIdx.x;
  float4* p4 = (float4*)(att + row * 2048);
  float4 a = p4[threadIdx.x];
  float4 b = p4[threadIdx.x + 256];
  float mx = fmaxf(fmaxf(fmaxf(a.x, a.y), fmaxf(a.z, a.w)),
                   fmaxf(fmaxf(b.x, b.y), fmaxf(b.z, b.w)));
  __shared__ float red[8];
  mx = wave_red_max(mx);
  int wid = threadIdx.x >> 6, lane = threadIdx.x & 63;
  if (lane == 0) red[wid] = mx;
  __syncthreads();
  mx = fmaxf(fmaxf(red[0], red[1]), fmaxf(red[2], red[3]));
  a.x = __expf(a.x - mx);
  a.y = __expf(a.y - mx);
  a.z = __expf(a.z - mx);
  a.w = __expf(a.w - mx);
  b.x = __expf(b.x - mx);
  b.y = __expf(b.y - mx);
  b.z = __expf(b.z - mx);
  b.w = __expf(b.w - mx);
  float s = a.x + a.y + a.z + a.w + b.x + b.y + b.z + b.w;
  s = wave_red_sum(s);
  if (lane == 0) red[4 + wid] = s;
  __syncthreads();
  float inv = 1.0f / (red[4] + red[5] + red[6] + red[7]);
  a.x *= inv; a.y *= inv; a.z *= inv; a.w *= inv;
  b.x *= inv; b.y *= inv; b.z *= inv; b.w *= inv;
  p4[threadIdx.x] = a;
  p4[threadIdx.x + 256] = b;
}

extern "C" void kernel_launch(void* const* d_in, const int* in_sizes, int n_in,
                              void* d_out, int out_size, void* d_ws,
                              size_t ws_size, hipStream_t stream) {
  const float* input = (const float*)d_in[0];
  const float* output = (const float*)d_in[1];
  const float* q_w = (const float*)d_in[2];
  const float* q_b = (const float*)d_in[3];
  const float* k_w = (const float*)d_in[4];
  const float* k_b = (const float*)d_in[5];
  const float* v_w = (const float*)d_in[6];
  const float* v_b = (const float*)d_in[7];
  const float* p_w = (const float*)d_in[8];
  const float* p_b = (const float*)d_in[9];
  const float* ln_in_g = (const float*)d_in[10];
  const float* ln_in_b = (const float*)d_in[11];
  const float* ln_out_g = (const float*)d_in[12];
  const float* ln_out_b = (const float*)d_in[13];

  float* ws = (float*)d_ws;
  float* i_ln = ws;                    // 4*2048*768   = 6291456
  float* o_ln = i_ln + 6291456;        // 4*1024*1024  = 4194304
  float* q = o_ln + 4194304;           // 4194304
  float* k = q + 4194304;              // 4*2048*1024  = 8388608
  float* v = k + 8388608;              // 8388608
  float* ctrl = v + 8388608;           // 4194304
  float* att = (float*)d_out;          // 134217728
  float* out2 = att + 134217728LL;

  // LayerNorms
  ln_kernel<<<8192, 256, 0, stream>>>(input, ln_in_g, ln_in_b, i_ln, 768);
  ln_kernel<<<4096, 256, 0, stream>>>(output, ln_out_g, ln_out_b, o_ln, 1024);

  // q = o_ln @ q_w^T + q_b : M=4096 N=1024 K=1024
  gemm_kernel<false><<<dim3(64, 16, 1), 256, 0, stream>>>(
      o_ln, q_w, q_b, nullptr, q, 4096, 1024, 1024, 1024, 1024, 1024, 0, 0, 0,
      0, 0, 0, 1, 1.0f);
  // k = i_ln @ k_w^T + k_b : M=8192 N=1024 K=768
  gemm_kernel<false><<<dim3(128, 16, 1), 256, 0, stream>>>(
      i_ln, k_w, k_b, nullptr, k, 8192, 1024, 768, 768, 768, 1024, 0, 0, 0, 0,
      0, 0, 1, 1.0f);
  // v = i_ln @ v_w^T + v_b
  gemm_kernel<false><<<dim3(128, 16, 1), 256, 0, stream>>>(
      i_ln, v_w, v_b, nullptr, v, 8192, 1024, 768, 768, 768, 1024, 0, 0, 0, 0,
      0, 0, 1, 1.0f);

  // scores[b,h] = (q_h @ k_h^T) / 8 : per z=(b*16+h), M=1024 N=2048 K=64
  gemm_kernel<false><<<dim3(16, 32, 64), 256, 0, stream>>>(
      q, k, nullptr, nullptr, att, 1024, 2048, 64, 1024, 1024, 2048,
      (long long)1024 * 1024, 64, (long long)2048 * 1024, 64,
      (long long)16 * 1024 * 2048, (long long)1024 * 2048, 16, 0.125f);

  // softmax rows: B*H*N2 = 65536 rows of 2048, in place
  softmax_kernel<<<65536, 256, 0, stream>>>(att);

  // ctrl[b,h] = P @ V_h : M=1024 N=64 K=2048, W stored [K,N] strided
  gemm_kernel<true><<<dim3(16, 1, 64), 256, 0, stream>>>(
      att, v, nullptr, nullptr, ctrl, 1024, 64, 2048, 2048, 1024, 1024,
      (long long)16 * 1024 * 2048, (long long)1024 * 2048,
      (long long)2048 * 1024, 64, (long long)1024 * 1024, 64, 16, 1.0f);

  // out = output + ctrl @ proj_w^T + proj_b
  gemm_kernel<false><<<dim3(64, 16, 1), 256, 0, stream>>>(
      ctrl, p_w, p_b, output, out2, 4096, 1024, 1024, 1024, 1024, 1024, 0, 0,
      0, 0, 0, 0, 1, 1.0f);
}

// Round 2
// 669.992 us; speedup vs baseline: 1.9582x; 1.9582x over previous
//
#include <hip/hip_runtime.h>
#include <hip/hip_bf16.h>
#include <math.h>

// B=4, N1=2048, N2=1024, IN=768, OUT=1024, H=16, DH=64
// d_out = att_probs fp32 [4,16,1024,2048] ++ out fp32 [4,1024,1024]

typedef __attribute__((ext_vector_type(8))) short short8;
typedef __attribute__((ext_vector_type(4))) float f32x4;

__device__ __forceinline__ ushort f2b(float f) {
  __hip_bfloat16 h = __float2bfloat16(f);
  return *reinterpret_cast<ushort*>(&h);
}

// ---------------- fp32 -> bf16 convert (weights) ----------------
__global__ __launch_bounds__(256) void cvt_kernel(const float* __restrict__ src,
                                                  ushort* __restrict__ dst,
                                                  int n4) {
  int i = blockIdx.x * 256 + threadIdx.x;
  if (i >= n4) return;
  float4 v = ((const float4*)src)[i];
  ushort4 o;
  o.x = f2b(v.x); o.y = f2b(v.y); o.z = f2b(v.z); o.w = f2b(v.w);
  ((ushort4*)dst)[i] = o;
}

// ---------------- LayerNorm: one block per row, bf16 out ----------------
__device__ __forceinline__ float wave_red_sum(float v) {
#pragma unroll
  for (int o = 32; o; o >>= 1) v += __shfl_down(v, o);
  return v;
}

__global__ __launch_bounds__(256) void ln_kernel(
    const float* __restrict__ src, const float* __restrict__ g,
    const float* __restrict__ bta, ushort* __restrict__ dst, int D) {
  size_t row = blockIdx.x;
  const float* x = src + row * (size_t)D;
  ushort* y = dst + row * (size_t)D;
  int nv = D >> 2;
  float s = 0.f, s2 = 0.f;
  for (int i = threadIdx.x; i < nv; i += 256) {
    float4 v = ((const float4*)x)[i];
    s += v.x + v.y + v.z + v.w;
    s2 += v.x * v.x + v.y * v.y + v.z * v.z + v.w * v.w;
  }
  s = wave_red_sum(s);
  s2 = wave_red_sum(s2);
  __shared__ float red[8];
  int wid = threadIdx.x >> 6, lane = threadIdx.x & 63;
  if (lane == 0) { red[wid] = s; red[4 + wid] = s2; }
  __syncthreads();
  float ts = red[0] + red[1] + red[2] + red[3];
  float t2 = red[4] + red[5] + red[6] + red[7];
  float mu = ts / (float)D;
  float rstd = rsqrtf(t2 / (float)D - mu * mu + 1e-5f);
  for (int i = threadIdx.x; i < nv; i += 256) {
    float4 v = ((const float4*)x)[i];
    float4 gg = ((const float4*)g)[i];
    float4 bb = ((const float4*)bta)[i];
    ushort4 o;
    o.x = f2b((v.x - mu) * rstd * gg.x + bb.x);
    o.y = f2b((v.y - mu) * rstd * gg.y + bb.y);
    o.z = f2b((v.z - mu) * rstd * gg.z + bb.z);
    o.w = f2b((v.w - mu) * rstd * gg.w + bb.w);
    ((ushort4*)y)[i] = o;
  }
}

// ---------------- Generic bf16 MFMA GEMM, 128x128 tile ----------------
// C[m][n] = alpha * sum_k A[m][k]*W[n][k] (+bias[n]) (+resid[m][n])
// A bf16 [.,lda], W bf16 [.,ldw] (both row-major, W holds B^T), C fp32 or bf16.
// Batch z: off += (z/zdiv)*s1 + (z%zdiv)*s2 (element offsets).
template <bool CBF, bool BIAS, bool RES>
__global__ __launch_bounds__(256) void gemm_bf16(
    const ushort* __restrict__ A, const ushort* __restrict__ W,
    const float* __restrict__ bias, const float* __restrict__ resid, void* Cv,
    int K, int lda, int ldw, int ldc, long long sA1, long long sA2,
    long long sW1, long long sW2, long long sC1, long long sC2, int zdiv,
    float alpha) {
  __shared__ ushort As[128 * 40];
  __shared__ ushort Ws[128 * 40];
  int z = blockIdx.z;
  int zb = z / zdiv, zh = z % zdiv;
  const ushort* Ab = A + (size_t)zb * sA1 + (size_t)zh * sA2 +
                     (size_t)blockIdx.x * 128 * lda;
  const ushort* Wb = W + (size_t)zb * sW1 + (size_t)zh * sW2 +
                     (size_t)blockIdx.y * 128 * ldw;
  int tid = threadIdx.x, l = tid & 63, w = tid >> 6;
  int wr = w >> 1, wc = w & 1;
  f32x4 acc[4][4];
#pragma unroll
  for (int i = 0; i < 4; ++i)
#pragma unroll
    for (int j = 0; j < 4; ++j) acc[i][j] = (f32x4){0.f, 0.f, 0.f, 0.f};

  int r = tid >> 1, hh = tid & 1;
  int lrow = l & 15, lk = (l >> 4) * 8;
  for (int k0 = 0; k0 < K; k0 += 32) {
    uint4 a0 = *(const uint4*)(Ab + (size_t)r * lda + k0 + hh * 16);
    uint4 w0 = *(const uint4*)(Wb + (size_t)r * ldw + k0 + hh * 16);
    uint4 a1 = *(const uint4*)(Ab + (size_t)r * lda + k0 + hh * 16 + 8);
    uint4 w1 = *(const uint4*)(Wb + (size_t)r * ldw + k0 + hh * 16 + 8);
    *(uint4*)&As[r * 40 + hh * 16] = a0;
    *(uint4*)&As[r * 40 + hh * 16 + 8] = a1;
    *(uint4*)&Ws[r * 40 + hh * 16] = w0;
    *(uint4*)&Ws[r * 40 + hh * 16 + 8] = w1;
    __syncthreads();
    short8 af[4], bf[4];
#pragma unroll
    for (int fi = 0; fi < 4; ++fi)
      af[fi] = *(const short8*)&As[(wr * 64 + fi * 16 + lrow) * 40 + lk];
#pragma unroll
    for (int fj = 0; fj < 4; ++fj)
      bf[fj] = *(const short8*)&Ws[(wc * 64 + fj * 16 + lrow) * 40 + lk];
#pragma unroll
    for (int fi = 0; fi < 4; ++fi)
#pragma unroll
      for (int fj = 0; fj < 4; ++fj)
        acc[fi][fj] = __builtin_amdgcn_mfma_f32_16x16x32_bf16(
            af[fi], bf[fj], acc[fi][fj], 0, 0, 0);
    __syncthreads();
  }

  int m0 = blockIdx.x * 128, n0 = blockIdx.y * 128;
  size_t cb = (size_t)zb * sC1 + (size_t)zh * sC2;
#pragma unroll
  for (int fi = 0; fi < 4; ++fi)
#pragma unroll
    for (int fj = 0; fj < 4; ++fj) {
      int col = n0 + wc * 64 + fj * 16 + lrow;
      float bv = 0.f;
      if (BIAS) bv = bias[col];
#pragma unroll
      for (int r4 = 0; r4 < 4; ++r4) {
        int row = m0 + wr * 64 + fi * 16 + (l >> 4) * 4 + r4;
        float val = acc[fi][fj][r4] * alpha + bv;
        if (RES) val += resid[(size_t)row * ldc + col];
        if (CBF)
          ((ushort*)Cv)[cb + (size_t)row * ldc + col] = f2b(val);
        else
          ((float*)Cv)[cb + (size_t)row * ldc + col] = val;
      }
    }
}

// ---------------- Fused softmax + P@V ----------------
// grid (8 m-tiles, 64 bh). Reads raw scores S (fp32, att region of d_out),
// writes normalized probs P in place, computes ctrl = P @ V_h (bf16 out).
__global__ __launch_bounds__(256) void pv_kernel(float* __restrict__ att,
                                                 const ushort* __restrict__ v,
                                                 ushort* __restrict__ ctrl) {
  int m0 = blockIdx.x * 128;
  int bh = blockIdx.y;
  int b = bh >> 4, h = bh & 15;
  int tid = threadIdx.x, l = tid & 63, w = tid >> 6;

  float* Sb = att + (size_t)bh * 1024 * 2048 + (size_t)m0 * 2048;

  __shared__ float mrow[128];
  __shared__ float linv[128];
  __shared__ ushort Ps[128 * 40];
  __shared__ ushort Vs[64 * 40];

  // ---- pass 1: per-row max & sum(exp) ----
  for (int rr = 0; rr < 32; ++rr) {
    int row = w * 32 + rr;
    const float4* rp = (const float4*)(Sb + (size_t)row * 2048);
    float4 vv[8];
#pragma unroll
    for (int i = 0; i < 8; ++i) vv[i] = rp[l + i * 64];
    float m = -1e30f;
#pragma unroll
    for (int i = 0; i < 8; ++i)
      m = fmaxf(m, fmaxf(fmaxf(vv[i].x, vv[i].y), fmaxf(vv[i].z, vv[i].w)));
    float s = 0.f;
#pragma unroll
    for (int i = 0; i < 8; ++i) {
      s += __expf(vv[i].x - m) + __expf(vv[i].y - m) + __expf(vv[i].z - m) +
           __expf(vv[i].w - m);
    }
#pragma unroll
    for (int off = 1; off < 64; off <<= 1) {
      float mo = __shfl_xor(m, off);
      float so = __shfl_xor(s, off);
      float nm = fmaxf(m, mo);
      s = s * __expf(m - nm) + so * __expf(mo - nm);
      m = nm;
    }
    if (l == 0) {
      mrow[row] = m;
      linv[row] = 1.0f / s;
    }
  }
  __syncthreads();

  // ---- pass 2: k-loop: stage P (exp+normalize, write back) & V, MFMA ----
  const ushort* Vb = v + (size_t)b * 2048 * 1024 + h * 64;
  int wr = w >> 1, wc = w & 1;
  int lrow = l & 15, lk = (l >> 4) * 8;
  f32x4 acc[4][2];
#pragma unroll
  for (int i = 0; i < 4; ++i)
#pragma unroll
    for (int j = 0; j < 2; ++j) acc[i][j] = (f32x4){0.f, 0.f, 0.f, 0.f};

  int r = tid >> 1, hh = tid & 1;
  int kk = tid >> 3, n8 = (tid & 7) * 8;
  for (int k0 = 0; k0 < 2048; k0 += 32) {
    // stage P: 128 rows x 32 cols; thread does 16 fp32
    float* sp = Sb + (size_t)r * 2048 + k0 + hh * 16;
    float mr = mrow[r], li = linv[r];
#pragma unroll
    for (int i = 0; i < 4; ++i) {
      float4 sv = *(float4*)(sp + i * 4);
      float4 p;
      p.x = __expf(sv.x - mr) * li;
      p.y = __expf(sv.y - mr) * li;
      p.z = __expf(sv.z - mr) * li;
      p.w = __expf(sv.w - mr) * li;
      *(float4*)(sp + i * 4) = p;  // normalized probs -> d_out (in place)
      ushort4 pb;
      pb.x = f2b(p.x); pb.y = f2b(p.y); pb.z = f2b(p.z); pb.w = f2b(p.w);
      *(ushort4*)&Ps[r * 40 + hh * 16 + i * 4] = pb;
    }
    // stage V: Vs[n][kk] = V[k0+kk][n]; thread reads 8 consecutive n at one k
    {
      union { uint4 u; ushort s[8]; } gv;
      gv.u = *(const uint4*)(Vb + (size_t)(k0 + kk) * 1024 + n8);
#pragma unroll
      for (int j = 0; j < 8; ++j) Vs[(n8 + j) * 40 + kk] = gv.s[j];
    }
    __syncthreads();
    short8 af[4], bf[2];
#pragma unroll
    for (int fi = 0; fi < 4; ++fi)
      af[fi] = *(const short8*)&Ps[(wr * 64 + fi * 16 + lrow) * 40 + lk];
#pragma unroll
    for (int fj = 0; fj < 2; ++fj)
      bf[fj] = *(const short8*)&Vs[(wc * 32 + fj * 16 + lrow) * 40 + lk];
#pragma unroll
    for (int fi = 0; fi < 4; ++fi)
#pragma unroll
      for (int fj = 0; fj < 2; ++fj)
        acc[fi][fj] = __builtin_amdgcn_mfma_f32_16x16x32_bf16(
            af[fi], bf[fj], acc[fi][fj], 0, 0, 0);
    __syncthreads();
  }

  // epilogue: ctrl bf16 [4096][1024]
#pragma unroll
  for (int fi = 0; fi < 4; ++fi)
#pragma unroll
    for (int fj = 0; fj < 2; ++fj) {
      int colh = wc * 32 + fj * 16 + lrow;
#pragma unroll
      for (int r4 = 0; r4 < 4; ++r4) {
        int row = m0 + wr * 64 + fi * 16 + (l >> 4) * 4 + r4;
        ctrl[((size_t)(b * 1024 + row)) * 1024 + h * 64 + colh] =
            f2b(acc[fi][fj][r4]);
      }
    }
}

extern "C" void kernel_launch(void* const* d_in, const int* in_sizes, int n_in,
                              void* d_out, int out_size, void* d_ws,
                              size_t ws_size, hipStream_t stream) {
  const float* input = (const float*)d_in[0];
  const float* output = (const float*)d_in[1];
  const float* q_w = (const float*)d_in[2];
  const float* q_b = (const float*)d_in[3];
  const float* k_w = (const float*)d_in[4];
  const float* k_b = (const float*)d_in[5];
  const float* v_w = (const float*)d_in[6];
  const float* v_b = (const float*)d_in[7];
  const float* p_w = (const float*)d_in[8];
  const float* p_b = (const float*)d_in[9];
  const float* ln_in_g = (const float*)d_in[10];
  const float* ln_in_b = (const float*)d_in[11];
  const float* ln_out_g = (const float*)d_in[12];
  const float* ln_out_b = (const float*)d_in[13];

  ushort* ws = (ushort*)d_ws;
  ushort* i_ln = ws;                    // 4*2048*768  = 6291456
  ushort* o_ln = i_ln + 6291456;        // 4*1024*1024 = 4194304
  ushort* qb = o_ln + 4194304;          // 4194304
  ushort* kb = qb + 4194304;            // 8388608
  ushort* vb = kb + 8388608;            // 8388608
  ushort* ctrl = vb + 8388608;          // 4194304
  ushort* qwb = ctrl + 4194304;         // 1048576
  ushort* kwb = qwb + 1048576;          // 786432
  ushort* vwb = kwb + 786432;           // 786432
  ushort* pwb = vwb + 786432;           // 1048576

  float* att = (float*)d_out;
  float* out2 = att + 134217728LL;

  // weight conversions
  cvt_kernel<<<1024, 256, 0, stream>>>(q_w, qwb, 262144);
  cvt_kernel<<<768, 256, 0, stream>>>(k_w, kwb, 196608);
  cvt_kernel<<<768, 256, 0, stream>>>(v_w, vwb, 196608);
  cvt_kernel<<<1024, 256, 0, stream>>>(p_w, pwb, 262144);

  // LayerNorms -> bf16
  ln_kernel<<<8192, 256, 0, stream>>>(input, ln_in_g, ln_in_b, i_ln, 768);
  ln_kernel<<<4096, 256, 0, stream>>>(output, ln_out_g, ln_out_b, o_ln, 1024);

  // q = o_ln @ q_w^T + q_b  (bf16 out)  M=4096 N=1024 K=1024
  gemm_bf16<true, true, false><<<dim3(32, 8, 1), 256, 0, stream>>>(
      o_ln, qwb, q_b, nullptr, qb, 1024, 1024, 1024, 1024, 0, 0, 0, 0, 0, 0,
      1, 1.0f);
  // k = i_ln @ k_w^T + k_b  M=8192 N=1024 K=768
  gemm_bf16<true, true, false><<<dim3(64, 8, 1), 256, 0, stream>>>(
      i_ln, kwb, k_b, nullptr, kb, 768, 768, 768, 1024, 0, 0, 0, 0, 0, 0, 1,
      1.0f);
  // v = i_ln @ v_w^T + v_b
  gemm_bf16<true, true, false><<<dim3(64, 8, 1), 256, 0, stream>>>(
      i_ln, vwb, v_b, nullptr, vb, 768, 768, 768, 1024, 0, 0, 0, 0, 0, 0, 1,
      1.0f);

  // scores: S[b,h] = (q_h @ k_h^T)/8  fp32 -> att. M=1024 N=2048 K=64, z=64
  gemm_bf16<false, false, false><<<dim3(8, 16, 64), 256, 0, stream>>>(
      qb, kb, nullptr, nullptr, att, 64, 1024, 1024, 2048, 1048576LL, 64LL,
      2097152LL, 64LL, 33554432LL, 2097152LL, 16, 0.125f);

  // fused softmax + P@V -> ctrl (bf16); writes normalized probs in place
  pv_kernel<<<dim3(8, 64), 256, 0, stream>>>(att, vb, ctrl);

  // out = output + ctrl @ proj_w^T + proj_b  (fp32) M=4096 N=1024 K=1024
  gemm_bf16<false, true, true><<<dim3(32, 8, 1), 256, 0, stream>>>(
      ctrl, pwb, p_b, output, out2, 1024, 1024, 1024, 1024, 0, 0, 0, 0, 0, 0,
      1, 1.0f);
}

// Round 3
// 375.551 us; speedup vs baseline: 3.4935x; 1.7840x over previous
//
#include <hip/hip_runtime.h>
#include <hip/hip_bf16.h>
#include <math.h>

// B=4, N1=2048, N2=1024, IN=768, OUT=1024, H=16, DH=64
// d_out = att_probs fp32 [4,16,1024,2048] ++ out fp32 [4,1024,1024]

typedef __attribute__((ext_vector_type(8))) short short8;
typedef __attribute__((ext_vector_type(4))) float f32x4;

__device__ __forceinline__ ushort f2b(float f) {
  __hip_bfloat16 h = __float2bfloat16(f);
  return *reinterpret_cast<ushort*>(&h);
}

// ---------------- fp32 -> bf16 convert (weights) ----------------
__global__ __launch_bounds__(256) void cvt_kernel(const float* __restrict__ src,
                                                  ushort* __restrict__ dst,
                                                  int n4) {
  int i = blockIdx.x * 256 + threadIdx.x;
  if (i >= n4) return;
  float4 v = ((const float4*)src)[i];
  ushort4 o;
  o.x = f2b(v.x); o.y = f2b(v.y); o.z = f2b(v.z); o.w = f2b(v.w);
  ((ushort4*)dst)[i] = o;
}

// ---------------- LayerNorm: one block per row, bf16 out ----------------
__device__ __forceinline__ float wave_red_sum(float v) {
#pragma unroll
  for (int o = 32; o; o >>= 1) v += __shfl_down(v, o);
  return v;
}

__global__ __launch_bounds__(256) void ln_kernel(
    const float* __restrict__ src, const float* __restrict__ g,
    const float* __restrict__ bta, ushort* __restrict__ dst, int D) {
  size_t row = blockIdx.x;
  const float* x = src + row * (size_t)D;
  ushort* y = dst + row * (size_t)D;
  int nv = D >> 2;
  float s = 0.f, s2 = 0.f;
  for (int i = threadIdx.x; i < nv; i += 256) {
    float4 v = ((const float4*)x)[i];
    s += v.x + v.y + v.z + v.w;
    s2 += v.x * v.x + v.y * v.y + v.z * v.z + v.w * v.w;
  }
  s = wave_red_sum(s);
  s2 = wave_red_sum(s2);
  __shared__ float red[8];
  int wid = threadIdx.x >> 6, lane = threadIdx.x & 63;
  if (lane == 0) { red[wid] = s; red[4 + wid] = s2; }
  __syncthreads();
  float ts = red[0] + red[1] + red[2] + red[3];
  float t2 = red[4] + red[5] + red[6] + red[7];
  float mu = ts / (float)D;
  float rstd = rsqrtf(t2 / (float)D - mu * mu + 1e-5f);
  for (int i = threadIdx.x; i < nv; i += 256) {
    float4 v = ((const float4*)x)[i];
    float4 gg = ((const float4*)g)[i];
    float4 bb = ((const float4*)bta)[i];
    ushort4 o;
    o.x = f2b((v.x - mu) * rstd * gg.x + bb.x);
    o.y = f2b((v.y - mu) * rstd * gg.y + bb.y);
    o.z = f2b((v.z - mu) * rstd * gg.z + bb.z);
    o.w = f2b((v.w - mu) * rstd * gg.w + bb.w);
    ((ushort4*)y)[i] = o;
  }
}

// ---------------- Generic bf16 MFMA GEMM, 128x128 tile ----------------
// C[m][n] = alpha*sum_k A[m][k]*W[n][k] (+bias) (+resid[m][n])
// BIASMODE: 0 none, 1 bias[col], 2 bias[row]
template <bool CBF, int BIASMODE, bool RES>
__global__ __launch_bounds__(256) void gemm_bf16(
    const ushort* __restrict__ A, const ushort* __restrict__ W,
    const float* __restrict__ bias, const float* __restrict__ resid, void* Cv,
    int K, int lda, int ldw, int ldc, long long sA1, long long sA2,
    long long sW1, long long sW2, long long sC1, long long sC2, int zdiv,
    float alpha) {
  __shared__ ushort As[128 * 40];
  __shared__ ushort Ws[128 * 40];
  int z = blockIdx.z;
  int zb = z / zdiv, zh = z % zdiv;
  const ushort* Ab = A + (size_t)zb * sA1 + (size_t)zh * sA2 +
                     (size_t)blockIdx.x * 128 * lda;
  const ushort* Wb = W + (size_t)zb * sW1 + (size_t)zh * sW2 +
                     (size_t)blockIdx.y * 128 * ldw;
  int tid = threadIdx.x, l = tid & 63, w = tid >> 6;
  int wr = w >> 1, wc = w & 1;
  f32x4 acc[4][4];
#pragma unroll
  for (int i = 0; i < 4; ++i)
#pragma unroll
    for (int j = 0; j < 4; ++j) acc[i][j] = (f32x4){0.f, 0.f, 0.f, 0.f};

  int r = tid >> 1, hh = tid & 1;
  int lrow = l & 15, lk = (l >> 4) * 8;
  for (int k0 = 0; k0 < K; k0 += 32) {
    uint4 a0 = *(const uint4*)(Ab + (size_t)r * lda + k0 + hh * 16);
    uint4 w0 = *(const uint4*)(Wb + (size_t)r * ldw + k0 + hh * 16);
    uint4 a1 = *(const uint4*)(Ab + (size_t)r * lda + k0 + hh * 16 + 8);
    uint4 w1 = *(const uint4*)(Wb + (size_t)r * ldw + k0 + hh * 16 + 8);
    *(uint4*)&As[r * 40 + hh * 16] = a0;
    *(uint4*)&As[r * 40 + hh * 16 + 8] = a1;
    *(uint4*)&Ws[r * 40 + hh * 16] = w0;
    *(uint4*)&Ws[r * 40 + hh * 16 + 8] = w1;
    __syncthreads();
    short8 af[4], bf[4];
#pragma unroll
    for (int fi = 0; fi < 4; ++fi)
      af[fi] = *(const short8*)&As[(wr * 64 + fi * 16 + lrow) * 40 + lk];
#pragma unroll
    for (int fj = 0; fj < 4; ++fj)
      bf[fj] = *(const short8*)&Ws[(wc * 64 + fj * 16 + lrow) * 40 + lk];
#pragma unroll
    for (int fi = 0; fi < 4; ++fi)
#pragma unroll
      for (int fj = 0; fj < 4; ++fj)
        acc[fi][fj] = __builtin_amdgcn_mfma_f32_16x16x32_bf16(
            af[fi], bf[fj], acc[fi][fj], 0, 0, 0);
    __syncthreads();
  }

  int m0 = blockIdx.x * 128, n0 = blockIdx.y * 128;
  size_t cb = (size_t)zb * sC1 + (size_t)zh * sC2;
#pragma unroll
  for (int fi = 0; fi < 4; ++fi)
#pragma unroll
    for (int fj = 0; fj < 4; ++fj) {
      int col = n0 + wc * 64 + fj * 16 + lrow;
      float bv = 0.f;
      if (BIASMODE == 1) bv = bias[col];
#pragma unroll
      for (int r4 = 0; r4 < 4; ++r4) {
        int row = m0 + wr * 64 + fi * 16 + (l >> 4) * 4 + r4;
        float val = acc[fi][fj][r4] * alpha + bv;
        if (BIASMODE == 2) val += bias[row];
        if (RES) val += resid[(size_t)row * ldc + col];
        if (CBF)
          ((ushort*)Cv)[cb + (size_t)row * ldc + col] = f2b(val);
        else
          ((float*)Cv)[cb + (size_t)row * ldc + col] = val;
      }
    }
}

// ---------------- Fused flash attention ----------------
// grid 1024 blocks: XCD-swizzled -> (bh, mtile). Block: 4 waves, 64 Q-rows.
// Pass A: stats (m,l) via QK^T recompute. Pass B: QK^T again, write normalized
// P to d_out (fp32), P->LDS bf16, PV MFMA from vt (d-major V).
__global__ __launch_bounds__(256, 4) void attn_kernel(
    const ushort* __restrict__ qb, const ushort* __restrict__ kb,
    const ushort* __restrict__ vt, float* __restrict__ att,
    ushort* __restrict__ ctrl) {
  __shared__ ushort Q_lds[64 * 72];
  __shared__ ushort K_lds[64 * 72];
  __shared__ ushort V_lds[64 * 72];
  __shared__ ushort P_lds[64 * 72];

  int bid = blockIdx.x;
  int vv = ((bid & 7) << 7) + (bid >> 3);  // XCD swizzle: 8 bh per XCD
  int bh = vv >> 4, mt = vv & 15;
  int b = bh >> 4, h = bh & 15;
  int m0 = mt * 64;
  int tid = threadIdx.x, l = tid & 63, w = tid >> 6;
  int lr = l & 15, lk = (l >> 4) * 8;

  // stage Q tile [64 rows][64 d]
#pragma unroll
  for (int it = 0; it < 2; ++it) {
    int idx = tid + it * 256;
    int row = idx >> 3, c8 = (idx & 7) * 8;
    *(uint4*)&Q_lds[row * 72 + c8] = *(const uint4*)(
        qb + (size_t)(b * 1024 + m0 + row) * 1024 + h * 64 + c8);
  }
  __syncthreads();
  short8 aq[2];
  aq[0] = *(const short8*)&Q_lds[(w * 16 + lr) * 72 + lk];
  aq[1] = *(const short8*)&Q_lds[(w * 16 + lr) * 72 + 32 + lk];

  float mrow[4], lsum[4];
#pragma unroll
  for (int r = 0; r < 4; ++r) { mrow[r] = -1e30f; lsum[r] = 0.f; }

  const size_t kbase = (size_t)b * 2048 * 1024 + h * 64;

  // ---- pass A: stats ----
  for (int k0 = 0; k0 < 2048; k0 += 64) {
#pragma unroll
    for (int it = 0; it < 2; ++it) {
      int idx = tid + it * 256;
      int row = idx >> 3, c8 = (idx & 7) * 8;
      *(uint4*)&K_lds[row * 72 + c8] =
          *(const uint4*)(kb + kbase + (size_t)(k0 + row) * 1024 + c8);
    }
    __syncthreads();
    f32x4 acc[4];
#pragma unroll
    for (int fj = 0; fj < 4; ++fj) {
      short8 bk0 = *(const short8*)&K_lds[(fj * 16 + lr) * 72 + lk];
      short8 bk1 = *(const short8*)&K_lds[(fj * 16 + lr) * 72 + 32 + lk];
      f32x4 a = (f32x4){0.f, 0.f, 0.f, 0.f};
      a = __builtin_amdgcn_mfma_f32_16x16x32_bf16(aq[0], bk0, a, 0, 0, 0);
      a = __builtin_amdgcn_mfma_f32_16x16x32_bf16(aq[1], bk1, a, 0, 0, 0);
      acc[fj] = a;
    }
#pragma unroll
    for (int r = 0; r < 4; ++r) {
      float cm =
          fmaxf(fmaxf(acc[0][r], acc[1][r]), fmaxf(acc[2][r], acc[3][r])) *
          0.125f;
#pragma unroll
      for (int off = 1; off < 16; off <<= 1) cm = fmaxf(cm, __shfl_xor(cm, off));
      float nm = fmaxf(mrow[r], cm);
      float cs = 0.f;
#pragma unroll
      for (int fj = 0; fj < 4; ++fj) cs += __expf(acc[fj][r] * 0.125f - nm);
#pragma unroll
      for (int off = 1; off < 16; off <<= 1) cs += __shfl_xor(cs, off);
      lsum[r] = lsum[r] * __expf(mrow[r] - nm) + cs;
      mrow[r] = nm;
    }
    __syncthreads();
  }
  float linv[4];
#pragma unroll
  for (int r = 0; r < 4; ++r) linv[r] = 1.0f / lsum[r];

  // ---- pass B: emit P + PV ----
  float* attp = att + (size_t)bh * 2048 * 1024 + (size_t)m0 * 2048;
  const size_t vtbase = (size_t)bh * 64 * 2048;
  f32x4 acco[4];
#pragma unroll
  for (int fd = 0; fd < 4; ++fd) acco[fd] = (f32x4){0.f, 0.f, 0.f, 0.f};

  for (int k0 = 0; k0 < 2048; k0 += 64) {
#pragma unroll
    for (int it = 0; it < 2; ++it) {
      int idx = tid + it * 256;
      int row = idx >> 3, c8 = (idx & 7) * 8;
      *(uint4*)&K_lds[row * 72 + c8] =
          *(const uint4*)(kb + kbase + (size_t)(k0 + row) * 1024 + c8);
      *(uint4*)&V_lds[row * 72 + c8] =
          *(const uint4*)(vt + vtbase + (size_t)row * 2048 + k0 + c8);
    }
    __syncthreads();
    f32x4 acc[4];
#pragma unroll
    for (int fj = 0; fj < 4; ++fj) {
      short8 bk0 = *(const short8*)&K_lds[(fj * 16 + lr) * 72 + lk];
      short8 bk1 = *(const short8*)&K_lds[(fj * 16 + lr) * 72 + 32 + lk];
      f32x4 a = (f32x4){0.f, 0.f, 0.f, 0.f};
      a = __builtin_amdgcn_mfma_f32_16x16x32_bf16(aq[0], bk0, a, 0, 0, 0);
      a = __builtin_amdgcn_mfma_f32_16x16x32_bf16(aq[1], bk1, a, 0, 0, 0);
      acc[fj] = a;
    }
#pragma unroll
    for (int fj = 0; fj < 4; ++fj)
#pragma unroll
      for (int r = 0; r < 4; ++r) {
        float p = __expf(acc[fj][r] * 0.125f - mrow[r]) * linv[r];
        int wrow = w * 16 + (l >> 4) * 4 + r;
        attp[(size_t)wrow * 2048 + k0 + fj * 16 + lr] = p;
        P_lds[wrow * 72 + fj * 16 + lr] = f2b(p);
      }
    __syncthreads();
    short8 ap0 = *(const short8*)&P_lds[(w * 16 + lr) * 72 + lk];
    short8 ap1 = *(const short8*)&P_lds[(w * 16 + lr) * 72 + 32 + lk];
#pragma unroll
    for (int fd = 0; fd < 4; ++fd) {
      short8 bv0 = *(const short8*)&V_lds[(fd * 16 + lr) * 72 + lk];
      short8 bv1 = *(const short8*)&V_lds[(fd * 16 + lr) * 72 + 32 + lk];
      acco[fd] =
          __builtin_amdgcn_mfma_f32_16x16x32_bf16(ap0, bv0, acco[fd], 0, 0, 0);
      acco[fd] =
          __builtin_amdgcn_mfma_f32_16x16x32_bf16(ap1, bv1, acco[fd], 0, 0, 0);
    }
    __syncthreads();
  }

#pragma unroll
  for (int fd = 0; fd < 4; ++fd)
#pragma unroll
    for (int r = 0; r < 4; ++r) {
      int wrow = w * 16 + (l >> 4) * 4 + r;
      ctrl[(size_t)(b * 1024 + m0 + wrow) * 1024 + h * 64 + fd * 16 + lr] =
          f2b(acco[fd][r]);
    }
}

extern "C" void kernel_launch(void* const* d_in, const int* in_sizes, int n_in,
                              void* d_out, int out_size, void* d_ws,
                              size_t ws_size, hipStream_t stream) {
  const float* input = (const float*)d_in[0];
  const float* output = (const float*)d_in[1];
  const float* q_w = (const float*)d_in[2];
  const float* q_b = (const float*)d_in[3];
  const float* k_w = (const float*)d_in[4];
  const float* k_b = (const float*)d_in[5];
  const float* v_w = (const float*)d_in[6];
  const float* v_b = (const float*)d_in[7];
  const float* p_w = (const float*)d_in[8];
  const float* p_b = (const float*)d_in[9];
  const float* ln_in_g = (const float*)d_in[10];
  const float* ln_in_b = (const float*)d_in[11];
  const float* ln_out_g = (const float*)d_in[12];
  const float* ln_out_b = (const float*)d_in[13];

  ushort* ws = (ushort*)d_ws;
  ushort* i_ln = ws;                    // 4*2048*768  = 6291456
  ushort* o_ln = i_ln + 6291456;        // 4194304
  ushort* qb = o_ln + 4194304;          // 4194304
  ushort* kb = qb + 4194304;            // 8388608
  ushort* vt = kb + 8388608;            // 8388608  [4][1024 d][2048 k]
  ushort* ctrl = vt + 8388608;          // 4194304
  ushort* qwb = ctrl + 4194304;         // 1048576
  ushort* kwb = qwb + 1048576;          // 786432
  ushort* vwb = kwb + 786432;           // 786432
  ushort* pwb = vwb + 786432;           // 1048576

  float* att = (float*)d_out;
  float* out2 = att + 134217728LL;

  cvt_kernel<<<1024, 256, 0, stream>>>(q_w, qwb, 262144);
  cvt_kernel<<<768, 256, 0, stream>>>(k_w, kwb, 196608);
  cvt_kernel<<<768, 256, 0, stream>>>(v_w, vwb, 196608);
  cvt_kernel<<<1024, 256, 0, stream>>>(p_w, pwb, 262144);

  ln_kernel<<<8192, 256, 0, stream>>>(input, ln_in_g, ln_in_b, i_ln, 768);
  ln_kernel<<<4096, 256, 0, stream>>>(output, ln_out_g, ln_out_b, o_ln, 1024);

  // q = o_ln @ q_w^T + q_b  (bf16) M=4096 N=1024 K=1024
  gemm_bf16<true, 1, false><<<dim3(32, 8, 1), 256, 0, stream>>>(
      o_ln, qwb, q_b, nullptr, qb, 1024, 1024, 1024, 1024, 0, 0, 0, 0, 0, 0,
      1, 1.0f);
  // k = i_ln @ k_w^T + k_b  (bf16) M=8192 N=1024 K=768
  gemm_bf16<true, 1, false><<<dim3(64, 8, 1), 256, 0, stream>>>(
      i_ln, kwb, k_b, nullptr, kb, 768, 768, 768, 1024, 0, 0, 0, 0, 0, 0, 1,
      1.0f);
  // vt[b] = v_w @ i_ln[b]^T + v_b[row]  (bf16) M=1024(d) N=2048(k) K=768, z=4
  gemm_bf16<true, 2, false><<<dim3(8, 16, 4), 256, 0, stream>>>(
      vwb, i_ln, v_b, nullptr, vt, 768, 768, 768, 2048, 0, 0,
      (long long)2048 * 768, 0, (long long)1024 * 2048, 0, 1, 1.0f);

  // fused attention: scores + softmax + P-write + PV
  attn_kernel<<<dim3(1024), 256, 0, stream>>>(qb, kb, vt, att, ctrl);

  // out = output + ctrl @ proj_w^T + proj_b (fp32) M=4096 N=1024 K=1024
  gemm_bf16<false, 1, true><<<dim3(32, 8, 1), 256, 0, stream>>>(
      ctrl, pwb, p_b, output, out2, 1024, 1024, 1024, 1024, 0, 0, 0, 0, 0, 0,
      1, 1.0f);
}